// Round 13
// baseline (286.598 us; speedup 1.0000x reference)
//
#include <hip/hip_runtime.h>
#include <math.h>

#define N_NODES 10000
#define F_IN_D  256
#define H_DIM   128
#define C_OUTD  40
#define NHEADS  8
#define NEDGES  160000
#define ETOT    (NEDGES + N_NODES)
#define SCALE_F 0.25f  /* 1/sqrt(16) */
#define TILES_N 157    /* ceil(10000/64) */

typedef __attribute__((ext_vector_type(8))) short bf16x8;   // 8 bf16 = 4 VGPRs
typedef __attribute__((ext_vector_type(4))) float f32x4;
typedef __attribute__((ext_vector_type(2))) float f32x2;

__device__ __forceinline__ unsigned short f2bf(float f) {
    unsigned int u = __float_as_uint(f);
    unsigned int r = (u + 0x7FFFu + ((u >> 16) & 1u)) >> 16;  // RNE
    return (unsigned short)r;
}
__device__ __forceinline__ float bf2f(unsigned short h) {
    return __uint_as_float(((unsigned int)h) << 16);
}
__device__ __forceinline__ unsigned char f2fp8(float v) {
    int pk = __builtin_amdgcn_cvt_pk_fp8_f32(v, v, 0, false);  // OCP e4m3fn
    return (unsigned char)(pk & 0xff);
}

// ---------------- graph preprocessing ----------------

__global__ void k_deg_count(const int* __restrict__ col, int* degi) {
    int e = blockIdx.x * 256 + threadIdx.x;
    if (e < NEDGES) atomicAdd(&degi[col[e]], 1);
}

__global__ void k_scan(const int* __restrict__ degi, int* offsets, int* cursor) {
    __shared__ int part[256];
    int tid = threadIdx.x;
    int s = 0;
    if (tid < 250) {
        const int4* d4 = (const int4*)degi;
        for (int i = 0; i < 10; ++i) {
            int4 v = d4[tid * 10 + i];
            s += v.x + v.y + v.z + v.w;
        }
    }
    part[tid] = s;
    __syncthreads();
    for (int off = 1; off < 256; off <<= 1) {
        int v = 0;
        if (tid >= off) v = part[tid - off];
        __syncthreads();
        part[tid] += v;
        __syncthreads();
    }
    if (tid < 250) {
        int base = part[tid] - s;  // exclusive prefix
        int beg = tid * 40;
        for (int i = 0; i < 40; ++i) {
            offsets[beg + i] = base;
            cursor[beg + i]  = 0;
            base += degi[beg + i];
        }
    }
}

__global__ void k_scatter(const int* __restrict__ row, const int* __restrict__ col,
                          const int* __restrict__ degi, const int* __restrict__ offsets,
                          int* cursor, int* csr_row, float* csr_norm) {
    int e = blockIdx.x * 256 + threadIdx.x;
    if (e >= ETOT) return;
    int r, c;
    if (e < NEDGES) { r = row[e]; c = col[e]; }
    else            { r = c = e - NEDGES; }   // self-loop
    int slot = offsets[c] + atomicAdd(&cursor[c], 1);
    float dr = rsqrtf((float)degi[r]);
    float dc = rsqrtf((float)degi[c]);
    csr_row[slot]  = r;
    csr_norm[slot] = dr * dc;
}

// ---------------- fused prep: deg_init + x cast + weight casts (independent) ----

__global__ void k_prep(const float* __restrict__ x, unsigned short* __restrict__ xb,
                       const float* __restrict__ w1, const float* __restrict__ wq,
                       const float* __restrict__ wk, const float* __restrict__ wv,
                       const float* __restrict__ w2,
                       unsigned short* __restrict__ W1T, unsigned short* __restrict__ WTq,
                       unsigned short* __restrict__ WTk, unsigned short* __restrict__ WTv,
                       unsigned short* __restrict__ W2T, int* __restrict__ degi) {
    int b = blockIdx.x;
    if (b < 2500) {
        int i = b * 256 + threadIdx.x;       // 2500*256*4 == 2560000 exactly
        float4 v = *(const float4*)&x[(size_t)i * 4];
        ushort4 o;
        o.x = f2bf(v.x); o.y = f2bf(v.y); o.z = f2bf(v.z); o.w = f2bf(v.w);
        *(ushort4*)&xb[(size_t)i * 4] = o;
    } else if (b < 3228) {
        int e = (b - 2500) * 256 + threadIdx.x;
        if (e < 32768) {
            int n = e >> 8, k = e & 255;
            W1T[e] = f2bf(w1[k * H_DIM + n]);
        } else if (e < 180224) {
            int e2 = e - 32768;
            int mat = e2 >> 14;          // 0..8
            int r   = e2 & 16383;
            int n = r >> 7, k = r & 127;
            int l = mat / 3, ws = mat % 3;
            const float*    src = (ws == 0) ? wq  : (ws == 1) ? wk  : wv;
            unsigned short* dst = (ws == 0) ? WTq : (ws == 1) ? WTk : WTv;
            dst[l * 16384 + n * H_DIM + k] = f2bf(src[l * 16384 + k * H_DIM + n]);
        } else if (e < 186368) {
            int e3 = e - 180224;
            int c = e3 >> 7, k = e3 & 127;
            W2T[c * H_DIM + k] = (c < C_OUTD) ? f2bf(w2[k * C_OUTD + c]) : 0;
        }
    } else {
        int i = (b - 3228) * 256 + threadIdx.x;
        if (i < N_NODES) degi[i] = 1;    // self-loop
    }
}

// ---------------- MFMA lin1: X0 = relu(x_bf @ W1 + b1), bf16 out ----------------
// nct RUNTIME arg (=8): prevents full-unroll spill (K=256 -> B-in-regs
// wouldn't fit here, unlike k_qkv_mfma).

__global__ __launch_bounds__(256) void k_lin1_mfma(const unsigned short* __restrict__ Xb,
                                                   const unsigned short* __restrict__ W1T,
                                                   const float* __restrict__ b1,
                                                   unsigned short* __restrict__ X0,
                                                   int nct) {
    int tid = threadIdx.x;
    int wid = tid >> 6, lane = tid & 63;
    int m = lane & 15, quad = lane >> 4;
    int rowA = blockIdx.x * 64 + wid * 16 + m;      // A overread past N_NODES stays in ws
    bf16x8 af[8];
    const unsigned short* ap = Xb + (size_t)rowA * F_IN_D + quad * 8;
    #pragma unroll
    for (int s = 0; s < 8; ++s)
        af[s] = __builtin_bit_cast(bf16x8, *(const uint4*)(ap + s * 32));
    int row0 = blockIdx.x * 64 + wid * 16 + quad * 4;
    for (int ct = 0; ct < nct; ++ct) {
        int col = ct * 16 + m;
        const unsigned short* bp = W1T + (size_t)col * F_IN_D + quad * 8;
        f32x4 acc = {0.f, 0.f, 0.f, 0.f};
        #pragma unroll
        for (int s = 0; s < 8; ++s) {
            bf16x8 bfr = __builtin_bit_cast(bf16x8, *(const uint4*)(bp + s * 32));
            acc = __builtin_amdgcn_mfma_f32_16x16x32_bf16(af[s], bfr, acc, 0, 0, 0);
        }
        float bb = b1[col];
        #pragma unroll
        for (int rg = 0; rg < 4; ++rg) {
            int r = row0 + rg;
            if (r < N_NODES)
                X0[(size_t)r * H_DIM + col] = f2bf(fmaxf(acc[rg] + bb, 0.f));
        }
    }
}

// ---------------- MFMA fused QKV projection (B-in-registers) ----------------
// grid = (1+2t)*TILES_N; mode 0 = Q (fp32 out), 1..t = K slices, t+1..2t = V.
// K/V: fp8 e4m3, layout [node][slice(3)][128].
// W (32 KB) preloaded entirely into VGPRs: 32 independent loads up front (max
// MLP), then back-to-back MFMA. ~175 VGPR by hand-count -- watch VGPR_Count:
// 256 means spill, revert.

__global__ __launch_bounds__(256) void k_qkv_mfma(const unsigned short* __restrict__ XHb,
                                                  const unsigned short* __restrict__ WTq,
                                                  const unsigned short* __restrict__ WTk,
                                                  const unsigned short* __restrict__ WTv,
                                                  const float* __restrict__ bq,
                                                  const float* __restrict__ bk,
                                                  const float* __restrict__ bv,
                                                  float* __restrict__ Qb,
                                                  unsigned char* __restrict__ Kb,
                                                  unsigned char* __restrict__ Vb,
                                                  int l, int t) {
    int tid = threadIdx.x;
    int wid = tid >> 6, lane = tid & 63;
    int m = lane & 15, quad = lane >> 4;
    int mi = blockIdx.x / TILES_N;
    int rt = blockIdx.x % TILES_N;
    const unsigned short* WT; const float* bias; int slice, mode;
    if (mi == 0)      { WT = WTq; bias = bq; slice = l;          mode = 0; }
    else if (mi <= t) { WT = WTk; bias = bk; slice = mi - 1;     mode = 1; }
    else              { WT = WTv; bias = bv; slice = mi - t - 1; mode = 2; }
    const unsigned short* A = XHb + (size_t)slice * N_NODES * H_DIM;
    int rowA = rt * 64 + wid * 16 + m;
    bf16x8 af[4];
    const unsigned short* ap = A + (size_t)rowA * H_DIM + quad * 8;
    #pragma unroll
    for (int s = 0; s < 4; ++s)
        af[s] = __builtin_bit_cast(bf16x8, *(const uint4*)(ap + s * 32));

    // preload the whole W tile for this wave's 8 col-tiles (32 x uint4)
    bf16x8 bf[8][4];
    #pragma unroll
    for (int ct = 0; ct < 8; ++ct) {
        const unsigned short* bp = WT + (size_t)(ct * 16 + m) * H_DIM + quad * 8;
        #pragma unroll
        for (int s = 0; s < 4; ++s)
            bf[ct][s] = __builtin_bit_cast(bf16x8, *(const uint4*)(bp + s * 32));
    }

    int row0 = rt * 64 + wid * 16 + quad * 4;
    unsigned char* OutB = (mode == 1) ? Kb : Vb;
    #pragma unroll
    for (int ct = 0; ct < 8; ++ct) {
        int col = ct * 16 + m;
        f32x4 acc = {0.f, 0.f, 0.f, 0.f};
        #pragma unroll
        for (int s = 0; s < 4; ++s)
            acc = __builtin_amdgcn_mfma_f32_16x16x32_bf16(af[s], bf[ct][s], acc, 0, 0, 0);
        float bb = bias[col];
        #pragma unroll
        for (int rg = 0; rg < 4; ++rg) {
            int r = row0 + rg;
            if (r < N_NODES) {
                float v = acc[rg] + bb;
                if (mode == 0) Qb[(size_t)r * H_DIM + col] = v;
                else OutB[((size_t)r * 3 + slice) * H_DIM + col] = f2fp8(v);
            }
        }
    }
}

// ---------------- fused per-node attention aggregation (wave-per-node) ----------------
// 256 threads = 4 waves = 4 nodes. fp8 K/V: 4 dims/lane, 32 lanes cover 128
// dims -> two edges per wave-iteration (half = lane>>5). Manual 1-deep
// software pipeline: iteration j+1's csr/K/V loads issued before j's compute.

template <int T>
__global__ __launch_bounds__(256) void k_attn_agg(const float* __restrict__ Q,
                                                  const unsigned int* __restrict__ K,
                                                  const unsigned int* __restrict__ V,
                                                  const int* __restrict__ csr_row,
                                                  const float* __restrict__ csr_norm,
                                                  const int* __restrict__ offsets,
                                                  const int* __restrict__ degi,
                                                  unsigned int* __restrict__ Xout) {
    int tid = threadIdx.x;
    int wid = tid >> 6, lane = tid & 63;
    int half = lane >> 5, ci = lane & 31;
    int n = blockIdx.x * 4 + wid;        // grid 2500*4 == N_NODES exactly
    f32x4 q4;
    {
        float4 t4 = *(const float4*)&Q[(size_t)n * H_DIM + ci * 4];
        q4[0] = t4.x * SCALE_F; q4[1] = t4.y * SCALE_F;
        q4[2] = t4.z * SCALE_F; q4[3] = t4.w * SCALE_F;
    }
    int start = offsets[n];
    int cnt   = degi[n];
    int npairs = (cnt + 1) >> 1;
    float a0 = 0.f, a1 = 0.f, a2 = 0.f, a3 = 0.f;

    // pipeline state (iteration j's inputs)
    float nrm_c;
    unsigned int kw_c[T], vw_c[T];
    {
        int e0 = half;                   // j = 0
        int valid = e0 < cnt;
        int idx = start + (valid ? e0 : 0);
        int r = csr_row[idx];
        nrm_c = valid ? csr_norm[idx] : 0.f;
        const unsigned int* kp = K + (size_t)r * 96 + ci;
        const unsigned int* vp = V + (size_t)r * 96 + ci;
        #pragma unroll
        for (int s = 0; s < T; ++s) { kw_c[s] = kp[s * 32]; vw_c[s] = vp[s * 32]; }
    }

    for (int j = 0; j < npairs; ++j) {
        // issue j+1's loads before computing j
        float nrm_n = 0.f;
        unsigned int kw_n[T], vw_n[T];
        if (j + 1 < npairs) {
            int e1 = 2 * (j + 1) + half;
            int valid = e1 < cnt;
            int idx = start + (valid ? e1 : 0);
            int r = csr_row[idx];
            nrm_n = valid ? csr_norm[idx] : 0.f;
            const unsigned int* kp = K + (size_t)r * 96 + ci;
            const unsigned int* vp = V + (size_t)r * 96 + ci;
            #pragma unroll
            for (int s = 0; s < T; ++s) { kw_n[s] = kp[s * 32]; vw_n[s] = vp[s * 32]; }
        } else {
            #pragma unroll
            for (int s = 0; s < T; ++s) { kw_n[s] = 0; vw_n[s] = 0; }
        }

        // compute with j's data
        float sc[T];
        #pragma unroll
        for (int s = 0; s < T; ++s) {
            f32x2 klo = __builtin_amdgcn_cvt_pk_f32_fp8(kw_c[s], false);
            f32x2 khi = __builtin_amdgcn_cvt_pk_f32_fp8(kw_c[s], true);
            float p = q4[0] * klo[0] + q4[1] * klo[1] + q4[2] * khi[0] + q4[3] * khi[1];
            p += __shfl_xor(p, 1, 4);
            p += __shfl_xor(p, 2, 4);
            sc[s] = p;                   // all 4 lanes of the head hold the dot
        }
        float m = 0.f;
        #pragma unroll
        for (int s = 0; s < T; ++s) m = fmaxf(m, sc[s]);
        float den = __expf(-m);          // restricted-softmax null slot
        float mv0 = 0.f, mv1 = 0.f, mv2 = 0.f, mv3 = 0.f;
        #pragma unroll
        for (int s = 0; s < T; ++s) {
            float w = __expf(sc[s] - m);
            den += w;
            f32x2 vlo = __builtin_amdgcn_cvt_pk_f32_fp8(vw_c[s], false);
            f32x2 vhi = __builtin_amdgcn_cvt_pk_f32_fp8(vw_c[s], true);
            mv0 += w * vlo[0]; mv1 += w * vlo[1];
            mv2 += w * vhi[0]; mv3 += w * vhi[1];
        }
        float ws = __fdividef(nrm_c, den);
        a0 += ws * mv0; a1 += ws * mv1; a2 += ws * mv2; a3 += ws * mv3;

        // rotate
        nrm_c = nrm_n;
        #pragma unroll
        for (int s = 0; s < T; ++s) { kw_c[s] = kw_n[s]; vw_c[s] = vw_n[s]; }
    }
    // combine the two edge-halves
    a0 += __shfl_xor(a0, 32, 64);
    a1 += __shfl_xor(a1, 32, 64);
    a2 += __shfl_xor(a2, 32, 64);
    a3 += __shfl_xor(a3, 32, 64);
    if (half == 0) {
        uint2 o;
        o.x = ((unsigned int)f2bf(fmaxf(a1, 0.f)) << 16) | (unsigned int)f2bf(fmaxf(a0, 0.f));
        o.y = ((unsigned int)f2bf(fmaxf(a3, 0.f)) << 16) | (unsigned int)f2bf(fmaxf(a2, 0.f));
        *(uint2*)&Xout[(size_t)n * 64 + ci * 2] = o;   // relu, packed bf16
    }
}

// ---------------- MFMA lin2 + fused log_softmax ----------------

__global__ __launch_bounds__(256) void k_lin2_mfma(const unsigned short* __restrict__ X,
                                                   const unsigned short* __restrict__ W2T,
                                                   const float* __restrict__ b2,
                                                   float* __restrict__ out) {
    int tid = threadIdx.x;
    int wid = tid >> 6, lane = tid & 63;
    int m = lane & 15, quad = lane >> 4;
    int rowA = blockIdx.x * 64 + wid * 16 + m;      // overread past N_NODES stays in ws
    bf16x8 af[4];
    const unsigned short* ap = X + (size_t)rowA * H_DIM + quad * 8;
    #pragma unroll
    for (int s = 0; s < 4; ++s)
        af[s] = __builtin_bit_cast(bf16x8, *(const uint4*)(ap + s * 32));

    f32x4 acc0 = {0.f, 0.f, 0.f, 0.f};
    f32x4 acc1 = {0.f, 0.f, 0.f, 0.f};
    f32x4 acc2 = {0.f, 0.f, 0.f, 0.f};
    const unsigned short* bp0 = W2T + (size_t)(m)      * H_DIM + quad * 8;
    const unsigned short* bp1 = W2T + (size_t)(16 + m) * H_DIM + quad * 8;
    const unsigned short* bp2 = W2T + (size_t)(32 + m) * H_DIM + quad * 8;
    #pragma unroll
    for (int s = 0; s < 4; ++s) {
        bf16x8 b0 = __builtin_bit_cast(bf16x8, *(const uint4*)(bp0 + s * 32));
        acc0 = __builtin_amdgcn_mfma_f32_16x16x32_bf16(af[s], b0, acc0, 0, 0, 0);
        bf16x8 b1 = __builtin_bit_cast(bf16x8, *(const uint4*)(bp1 + s * 32));
        acc1 = __builtin_amdgcn_mfma_f32_16x16x32_bf16(af[s], b1, acc1, 0, 0, 0);
        bf16x8 b2f = __builtin_bit_cast(bf16x8, *(const uint4*)(bp2 + s * 32));
        acc2 = __builtin_amdgcn_mfma_f32_16x16x32_bf16(af[s], b2f, acc2, 0, 0, 0);
    }

    float bb0 = b2[m], bb1 = b2[16 + m];
    float bb2 = (m < 8) ? b2[32 + m] : 0.f;
    int row0 = blockIdx.x * 64 + wid * 16 + quad * 4;
    #pragma unroll
    for (int rg = 0; rg < 4; ++rg) {
        int r = row0 + rg;
        float v0 = acc0[rg] + bb0;
        float v1 = acc1[rg] + bb1;
        float v2 = (m < 8) ? (acc2[rg] + bb2) : -INFINITY;
        float mx = fmaxf(fmaxf(v0, v1), v2);
        #pragma unroll
        for (int o = 8; o > 0; o >>= 1) mx = fmaxf(mx, __shfl_xor(mx, o, 16));
        float sm = __expf(v0 - mx) + __expf(v1 - mx) + ((m < 8) ? __expf(v2 - mx) : 0.f);
        #pragma unroll
        for (int o = 8; o > 0; o >>= 1) sm += __shfl_xor(sm, o, 16);
        float lse = mx + __logf(sm);
        if (r < N_NODES) {
            out[(size_t)r * C_OUTD + m]      = v0 - lse;
            out[(size_t)r * C_OUTD + 16 + m] = v1 - lse;
            if (m < 8) out[(size_t)r * C_OUTD + 32 + m] = v2 - lse;
        }
    }
}

// ---------------- launcher ----------------

extern "C" void kernel_launch(void* const* d_in, const int* in_sizes, int n_in,
                              void* d_out, int out_size, void* d_ws, size_t ws_size,
                              hipStream_t stream) {
    const int*   ei      = (const int*)d_in[0];
    const int*   row     = ei;
    const int*   col     = ei + NEDGES;
    const float* x_param = (const float*)d_in[1];
    const float* lin1_w  = (const float*)d_in[2];
    const float* lin1_b  = (const float*)d_in[3];
    const float* wq      = (const float*)d_in[4];
    const float* wk      = (const float*)d_in[5];
    const float* wv      = (const float*)d_in[6];
    const float* bq      = (const float*)d_in[7];
    const float* bk      = (const float*)d_in[8];
    const float* bv      = (const float*)d_in[9];
    const float* lin2_w  = (const float*)d_in[10];
    const float* lin2_b  = (const float*)d_in[11];
    float*       out     = (float*)d_out;

    char* wbase = (char*)d_ws;
    size_t off = 0;
    auto alloc = [&](size_t bytes) -> void* {
        off = (off + 255) & ~(size_t)255;
        void* p = wbase + off;
        off += bytes;
        return p;
    };
    int*            degi     = (int*)           alloc((size_t)N_NODES * 4);
    int*            offsets  = (int*)           alloc((size_t)N_NODES * 4);
    int*            cursor   = (int*)           alloc((size_t)N_NODES * 4);
    int*            csr_row  = (int*)           alloc((size_t)ETOT * 4);
    float*          csr_norm = (float*)         alloc((size_t)ETOT * 4);
    unsigned short* xpb      = (unsigned short*)alloc((size_t)N_NODES * F_IN_D * 2);
    unsigned short* W1T      = (unsigned short*)alloc((size_t)H_DIM * F_IN_D * 2);
    unsigned short* WTq      = (unsigned short*)alloc((size_t)3 * H_DIM * H_DIM * 2);
    unsigned short* WTk      = (unsigned short*)alloc((size_t)3 * H_DIM * H_DIM * 2);
    unsigned short* WTv      = (unsigned short*)alloc((size_t)3 * H_DIM * H_DIM * 2);
    unsigned short* W2T      = (unsigned short*)alloc((size_t)48 * H_DIM * 2);
    unsigned short* XHb      = (unsigned short*)alloc((size_t)4 * N_NODES * H_DIM * 2);
    float*          Qb       = (float*)         alloc((size_t)N_NODES * H_DIM * 4);
    unsigned char*  Kb       = (unsigned char*) alloc((size_t)N_NODES * 3 * H_DIM);
    unsigned char*  Vb       = (unsigned char*) alloc((size_t)N_NODES * 3 * H_DIM);

    // fused prep: x cast + weight casts + deg init (independent tasks)
    k_prep<<<3268, 256, 0, stream>>>(x_param, xpb, lin1_w, wq, wk, wv, lin2_w,
                                     W1T, WTq, WTk, WTv, W2T, degi);
    k_deg_count<<<(NEDGES + 255) / 256, 256, 0, stream>>>(col, degi);
    k_scan     <<<1, 256, 0, stream>>>(degi, offsets, cursor);
    k_scatter  <<<(ETOT + 255) / 256, 256, 0, stream>>>(row, col, degi, offsets, cursor,
                                                        csr_row, csr_norm);

    // x0 = relu(x @ W1 + b1)  [MFMA, bf16 out]
    k_lin1_mfma<<<TILES_N, 256, 0, stream>>>(xpb, W1T, lin1_b, XHb, 8);

    for (int l = 0; l < 3; ++l) {
        int t = l + 1;
        k_qkv_mfma<<<(1 + 2 * t) * TILES_N, 256, 0, stream>>>(
            XHb, WTq + (size_t)l * 16384, WTk + (size_t)l * 16384, WTv + (size_t)l * 16384,
            bq + l * H_DIM, bk + l * H_DIM, bv + l * H_DIM,
            Qb, Kb, Vb, l, t);
        unsigned int* Xnext = (unsigned int*)(XHb + (size_t)(l + 1) * N_NODES * H_DIM);
        if (t == 1)
            k_attn_agg<1><<<2500, 256, 0, stream>>>(Qb, (const unsigned int*)Kb,
                                                    (const unsigned int*)Vb, csr_row,
                                                    csr_norm, offsets, degi, Xnext);
        else if (t == 2)
            k_attn_agg<2><<<2500, 256, 0, stream>>>(Qb, (const unsigned int*)Kb,
                                                    (const unsigned int*)Vb, csr_row,
                                                    csr_norm, offsets, degi, Xnext);
        else
            k_attn_agg<3><<<2500, 256, 0, stream>>>(Qb, (const unsigned int*)Kb,
                                                    (const unsigned int*)Vb, csr_row,
                                                    csr_norm, offsets, degi, Xnext);
    }

    k_lin2_mfma<<<TILES_N, 256, 0, stream>>>(XHb + (size_t)3 * N_NODES * H_DIM,
                                             W2T, lin2_b, out);
}

// Round 14
// 283.586 us; speedup vs baseline: 1.0106x; 1.0106x over previous
//
#include <hip/hip_runtime.h>
#include <math.h>

#define N_NODES 10000
#define F_IN_D  256
#define H_DIM   128
#define C_OUTD  40
#define NHEADS  8
#define NEDGES  160000
#define ETOT    (NEDGES + N_NODES)
#define SCALE_F 0.25f  /* 1/sqrt(16) */
#define TILES_N 157    /* ceil(10000/64) */

typedef __attribute__((ext_vector_type(8))) short bf16x8;   // 8 bf16 = 4 VGPRs
typedef __attribute__((ext_vector_type(4))) float f32x4;
typedef __attribute__((ext_vector_type(2))) float f32x2;

__device__ __forceinline__ unsigned short f2bf(float f) {
    unsigned int u = __float_as_uint(f);
    unsigned int r = (u + 0x7FFFu + ((u >> 16) & 1u)) >> 16;  // RNE
    return (unsigned short)r;
}
__device__ __forceinline__ float bf2f(unsigned short h) {
    return __uint_as_float(((unsigned int)h) << 16);
}
__device__ __forceinline__ unsigned char f2fp8(float v) {
    int pk = __builtin_amdgcn_cvt_pk_fp8_f32(v, v, 0, false);  // OCP e4m3fn
    return (unsigned char)(pk & 0xff);
}

// ---------------- graph preprocessing ----------------

__global__ void k_deg_count(const int* __restrict__ col, int* degi) {
    int e = blockIdx.x * 256 + threadIdx.x;
    if (e < NEDGES) atomicAdd(&degi[col[e]], 1);
}

__global__ void k_scan(const int* __restrict__ degi, int* offsets, int* cursor) {
    __shared__ int part[256];
    int tid = threadIdx.x;
    int s = 0;
    if (tid < 250) {
        const int4* d4 = (const int4*)degi;
        for (int i = 0; i < 10; ++i) {
            int4 v = d4[tid * 10 + i];
            s += v.x + v.y + v.z + v.w;
        }
    }
    part[tid] = s;
    __syncthreads();
    for (int off = 1; off < 256; off <<= 1) {
        int v = 0;
        if (tid >= off) v = part[tid - off];
        __syncthreads();
        part[tid] += v;
        __syncthreads();
    }
    if (tid < 250) {
        int base = part[tid] - s;  // exclusive prefix
        int beg = tid * 40;
        for (int i = 0; i < 40; ++i) {
            offsets[beg + i] = base;
            cursor[beg + i]  = 0;
            base += degi[beg + i];
        }
    }
}

__global__ void k_scatter(const int* __restrict__ row, const int* __restrict__ col,
                          const int* __restrict__ degi, const int* __restrict__ offsets,
                          int* cursor, int* csr_row, float* csr_norm) {
    int e = blockIdx.x * 256 + threadIdx.x;
    if (e >= ETOT) return;
    int r, c;
    if (e < NEDGES) { r = row[e]; c = col[e]; }
    else            { r = c = e - NEDGES; }   // self-loop
    int slot = offsets[c] + atomicAdd(&cursor[c], 1);
    float dr = rsqrtf((float)degi[r]);
    float dc = rsqrtf((float)degi[c]);
    csr_row[slot]  = r;
    csr_norm[slot] = dr * dc;
}

// ---------------- fused prep: deg_init + x cast + weight casts (independent) ----

__global__ void k_prep(const float* __restrict__ x, unsigned short* __restrict__ xb,
                       const float* __restrict__ w1, const float* __restrict__ wq,
                       const float* __restrict__ wk, const float* __restrict__ wv,
                       const float* __restrict__ w2,
                       unsigned short* __restrict__ W1T, unsigned short* __restrict__ WTq,
                       unsigned short* __restrict__ WTk, unsigned short* __restrict__ WTv,
                       unsigned short* __restrict__ W2T, int* __restrict__ degi) {
    int b = blockIdx.x;
    if (b < 2500) {
        int i = b * 256 + threadIdx.x;       // 2500*256*4 == 2560000 exactly
        float4 v = *(const float4*)&x[(size_t)i * 4];
        ushort4 o;
        o.x = f2bf(v.x); o.y = f2bf(v.y); o.z = f2bf(v.z); o.w = f2bf(v.w);
        *(ushort4*)&xb[(size_t)i * 4] = o;
    } else if (b < 3228) {
        int e = (b - 2500) * 256 + threadIdx.x;
        if (e < 32768) {
            int n = e >> 8, k = e & 255;
            W1T[e] = f2bf(w1[k * H_DIM + n]);
        } else if (e < 180224) {
            int e2 = e - 32768;
            int mat = e2 >> 14;          // 0..8
            int r   = e2 & 16383;
            int n = r >> 7, k = r & 127;
            int l = mat / 3, ws = mat % 3;
            const float*    src = (ws == 0) ? wq  : (ws == 1) ? wk  : wv;
            unsigned short* dst = (ws == 0) ? WTq : (ws == 1) ? WTk : WTv;
            dst[l * 16384 + n * H_DIM + k] = f2bf(src[l * 16384 + k * H_DIM + n]);
        } else if (e < 186368) {
            int e3 = e - 180224;
            int c = e3 >> 7, k = e3 & 127;
            W2T[c * H_DIM + k] = (c < C_OUTD) ? f2bf(w2[k * C_OUTD + c]) : 0;
        }
    } else {
        int i = (b - 3228) * 256 + threadIdx.x;
        if (i < N_NODES) degi[i] = 1;    // self-loop
    }
}

// ---------------- MFMA lin1: X0 = relu(x_bf @ W1 + b1), bf16 out ----------------
// nct RUNTIME arg (=8): prevents full-unroll spill (K=256 -> B-in-regs
// wouldn't fit here, unlike k_qkv_mfma).

__global__ __launch_bounds__(256) void k_lin1_mfma(const unsigned short* __restrict__ Xb,
                                                   const unsigned short* __restrict__ W1T,
                                                   const float* __restrict__ b1,
                                                   unsigned short* __restrict__ X0,
                                                   int nct) {
    int tid = threadIdx.x;
    int wid = tid >> 6, lane = tid & 63;
    int m = lane & 15, quad = lane >> 4;
    int rowA = blockIdx.x * 64 + wid * 16 + m;      // A overread past N_NODES stays in ws
    bf16x8 af[8];
    const unsigned short* ap = Xb + (size_t)rowA * F_IN_D + quad * 8;
    #pragma unroll
    for (int s = 0; s < 8; ++s)
        af[s] = __builtin_bit_cast(bf16x8, *(const uint4*)(ap + s * 32));
    int row0 = blockIdx.x * 64 + wid * 16 + quad * 4;
    for (int ct = 0; ct < nct; ++ct) {
        int col = ct * 16 + m;
        const unsigned short* bp = W1T + (size_t)col * F_IN_D + quad * 8;
        f32x4 acc = {0.f, 0.f, 0.f, 0.f};
        #pragma unroll
        for (int s = 0; s < 8; ++s) {
            bf16x8 bfr = __builtin_bit_cast(bf16x8, *(const uint4*)(bp + s * 32));
            acc = __builtin_amdgcn_mfma_f32_16x16x32_bf16(af[s], bfr, acc, 0, 0, 0);
        }
        float bb = b1[col];
        #pragma unroll
        for (int rg = 0; rg < 4; ++rg) {
            int r = row0 + rg;
            if (r < N_NODES)
                X0[(size_t)r * H_DIM + col] = f2bf(fmaxf(acc[rg] + bb, 0.f));
        }
    }
}

// ---------------- MFMA fused QKV projection (B-in-registers) ----------------
// grid = (1+2t)*TILES_N; mode 0 = Q (fp32 out), 1..t = K slices, t+1..2t = V.
// K/V: fp8 e4m3, layout [node][slice(3)][128].
// W (32 KB) preloaded entirely into VGPRs: 32 independent loads up front, then
// back-to-back MFMA.

__global__ __launch_bounds__(256) void k_qkv_mfma(const unsigned short* __restrict__ XHb,
                                                  const unsigned short* __restrict__ WTq,
                                                  const unsigned short* __restrict__ WTk,
                                                  const unsigned short* __restrict__ WTv,
                                                  const float* __restrict__ bq,
                                                  const float* __restrict__ bk,
                                                  const float* __restrict__ bv,
                                                  float* __restrict__ Qb,
                                                  unsigned char* __restrict__ Kb,
                                                  unsigned char* __restrict__ Vb,
                                                  int l, int t) {
    int tid = threadIdx.x;
    int wid = tid >> 6, lane = tid & 63;
    int m = lane & 15, quad = lane >> 4;
    int mi = blockIdx.x / TILES_N;
    int rt = blockIdx.x % TILES_N;
    const unsigned short* WT; const float* bias; int slice, mode;
    if (mi == 0)      { WT = WTq; bias = bq; slice = l;          mode = 0; }
    else if (mi <= t) { WT = WTk; bias = bk; slice = mi - 1;     mode = 1; }
    else              { WT = WTv; bias = bv; slice = mi - t - 1; mode = 2; }
    const unsigned short* A = XHb + (size_t)slice * N_NODES * H_DIM;
    int rowA = rt * 64 + wid * 16 + m;
    bf16x8 af[4];
    const unsigned short* ap = A + (size_t)rowA * H_DIM + quad * 8;
    #pragma unroll
    for (int s = 0; s < 4; ++s)
        af[s] = __builtin_bit_cast(bf16x8, *(const uint4*)(ap + s * 32));

    // preload the whole W tile for this wave's 8 col-tiles (32 x uint4)
    bf16x8 bf[8][4];
    #pragma unroll
    for (int ct = 0; ct < 8; ++ct) {
        const unsigned short* bp = WT + (size_t)(ct * 16 + m) * H_DIM + quad * 8;
        #pragma unroll
        for (int s = 0; s < 4; ++s)
            bf[ct][s] = __builtin_bit_cast(bf16x8, *(const uint4*)(bp + s * 32));
    }

    int row0 = rt * 64 + wid * 16 + quad * 4;
    unsigned char* OutB = (mode == 1) ? Kb : Vb;
    #pragma unroll
    for (int ct = 0; ct < 8; ++ct) {
        int col = ct * 16 + m;
        f32x4 acc = {0.f, 0.f, 0.f, 0.f};
        #pragma unroll
        for (int s = 0; s < 4; ++s)
            acc = __builtin_amdgcn_mfma_f32_16x16x32_bf16(af[s], bf[ct][s], acc, 0, 0, 0);
        float bb = bias[col];
        #pragma unroll
        for (int rg = 0; rg < 4; ++rg) {
            int r = row0 + rg;
            if (r < N_NODES) {
                float v = acc[rg] + bb;
                if (mode == 0) Qb[(size_t)r * H_DIM + col] = v;
                else OutB[((size_t)r * 3 + slice) * H_DIM + col] = f2fp8(v);
            }
        }
    }
}

// ---------------- fused per-node attention aggregation (wave-per-node) ----------------
// 256 threads = 4 waves = 4 nodes. fp8 K/V: 4 dims/lane (one uint), 32 lanes
// cover 128 dims -> TWO edges per wave-iteration (half = lane>>5).
// head h = (lane&31)>>2, reduction width 4; cross-half combine at end.
// K,V viewed as uint [node][slice(3)][32].
// NOTE: R13's manual software pipeline REGRESSED (+14 us): at VGPR=20 /
// 8 waves/SIMD the gather latency is already TLP-hidden; the rotation movs
// were pure added VALU work. Keep this plain form.

template <int T>
__global__ __launch_bounds__(256) void k_attn_agg(const float* __restrict__ Q,
                                                  const unsigned int* __restrict__ K,
                                                  const unsigned int* __restrict__ V,
                                                  const int* __restrict__ csr_row,
                                                  const float* __restrict__ csr_norm,
                                                  const int* __restrict__ offsets,
                                                  const int* __restrict__ degi,
                                                  unsigned int* __restrict__ Xout) {
    int tid = threadIdx.x;
    int wid = tid >> 6, lane = tid & 63;
    int half = lane >> 5, ci = lane & 31;
    int n = blockIdx.x * 4 + wid;        // grid 2500*4 == N_NODES exactly
    f32x4 q4;
    {
        float4 t4 = *(const float4*)&Q[(size_t)n * H_DIM + ci * 4];
        q4[0] = t4.x * SCALE_F; q4[1] = t4.y * SCALE_F;
        q4[2] = t4.z * SCALE_F; q4[3] = t4.w * SCALE_F;
    }
    int start = offsets[n];
    int cnt   = degi[n];
    int npairs = (cnt + 1) >> 1;
    float a0 = 0.f, a1 = 0.f, a2 = 0.f, a3 = 0.f;

    for (int j = 0; j < npairs; ++j) {
        int j2 = j * 2 + half;
        int valid = j2 < cnt;
        int idx = start + (valid ? j2 : 0);
        int   r   = csr_row[idx];
        float nrm = valid ? csr_norm[idx] : 0.f;
        const unsigned int* kp = K + (size_t)r * 96 + ci;
        const unsigned int* vp = V + (size_t)r * 96 + ci;
        unsigned int kw[T], vw[T];
        #pragma unroll
        for (int s = 0; s < T; ++s) { kw[s] = kp[s * 32]; vw[s] = vp[s * 32]; }
        float sc[T];
        #pragma unroll
        for (int s = 0; s < T; ++s) {
            f32x2 klo = __builtin_amdgcn_cvt_pk_f32_fp8(kw[s], false);
            f32x2 khi = __builtin_amdgcn_cvt_pk_f32_fp8(kw[s], true);
            float p = q4[0] * klo[0] + q4[1] * klo[1] + q4[2] * khi[0] + q4[3] * khi[1];
            p += __shfl_xor(p, 1, 4);
            p += __shfl_xor(p, 2, 4);
            sc[s] = p;                   // all 4 lanes of the head hold the dot
        }
        float m = 0.f;
        #pragma unroll
        for (int s = 0; s < T; ++s) m = fmaxf(m, sc[s]);
        float den = __expf(-m);          // restricted-softmax null slot
        float mv0 = 0.f, mv1 = 0.f, mv2 = 0.f, mv3 = 0.f;
        #pragma unroll
        for (int s = 0; s < T; ++s) {
            float w = __expf(sc[s] - m);
            den += w;
            f32x2 vlo = __builtin_amdgcn_cvt_pk_f32_fp8(vw[s], false);
            f32x2 vhi = __builtin_amdgcn_cvt_pk_f32_fp8(vw[s], true);
            mv0 += w * vlo[0]; mv1 += w * vlo[1];
            mv2 += w * vhi[0]; mv3 += w * vhi[1];
        }
        float ws = __fdividef(nrm, den);
        a0 += ws * mv0; a1 += ws * mv1; a2 += ws * mv2; a3 += ws * mv3;
    }
    // combine the two edge-halves
    a0 += __shfl_xor(a0, 32, 64);
    a1 += __shfl_xor(a1, 32, 64);
    a2 += __shfl_xor(a2, 32, 64);
    a3 += __shfl_xor(a3, 32, 64);
    if (half == 0) {
        uint2 o;
        o.x = ((unsigned int)f2bf(fmaxf(a1, 0.f)) << 16) | (unsigned int)f2bf(fmaxf(a0, 0.f));
        o.y = ((unsigned int)f2bf(fmaxf(a3, 0.f)) << 16) | (unsigned int)f2bf(fmaxf(a2, 0.f));
        *(uint2*)&Xout[(size_t)n * 64 + ci * 2] = o;   // relu, packed bf16
    }
}

// ---------------- MFMA lin2 + fused log_softmax ----------------

__global__ __launch_bounds__(256) void k_lin2_mfma(const unsigned short* __restrict__ X,
                                                   const unsigned short* __restrict__ W2T,
                                                   const float* __restrict__ b2,
                                                   float* __restrict__ out) {
    int tid = threadIdx.x;
    int wid = tid >> 6, lane = tid & 63;
    int m = lane & 15, quad = lane >> 4;
    int rowA = blockIdx.x * 64 + wid * 16 + m;      // overread past N_NODES stays in ws
    bf16x8 af[4];
    const unsigned short* ap = X + (size_t)rowA * H_DIM + quad * 8;
    #pragma unroll
    for (int s = 0; s < 4; ++s)
        af[s] = __builtin_bit_cast(bf16x8, *(const uint4*)(ap + s * 32));

    f32x4 acc0 = {0.f, 0.f, 0.f, 0.f};
    f32x4 acc1 = {0.f, 0.f, 0.f, 0.f};
    f32x4 acc2 = {0.f, 0.f, 0.f, 0.f};
    const unsigned short* bp0 = W2T + (size_t)(m)      * H_DIM + quad * 8;
    const unsigned short* bp1 = W2T + (size_t)(16 + m) * H_DIM + quad * 8;
    const unsigned short* bp2 = W2T + (size_t)(32 + m) * H_DIM + quad * 8;
    #pragma unroll
    for (int s = 0; s < 4; ++s) {
        bf16x8 b0 = __builtin_bit_cast(bf16x8, *(const uint4*)(bp0 + s * 32));
        acc0 = __builtin_amdgcn_mfma_f32_16x16x32_bf16(af[s], b0, acc0, 0, 0, 0);
        bf16x8 b1 = __builtin_bit_cast(bf16x8, *(const uint4*)(bp1 + s * 32));
        acc1 = __builtin_amdgcn_mfma_f32_16x16x32_bf16(af[s], b1, acc1, 0, 0, 0);
        bf16x8 b2f = __builtin_bit_cast(bf16x8, *(const uint4*)(bp2 + s * 32));
        acc2 = __builtin_amdgcn_mfma_f32_16x16x32_bf16(af[s], b2f, acc2, 0, 0, 0);
    }

    float bb0 = b2[m], bb1 = b2[16 + m];
    float bb2 = (m < 8) ? b2[32 + m] : 0.f;
    int row0 = blockIdx.x * 64 + wid * 16 + quad * 4;
    #pragma unroll
    for (int rg = 0; rg < 4; ++rg) {
        int r = row0 + rg;
        float v0 = acc0[rg] + bb0;
        float v1 = acc1[rg] + bb1;
        float v2 = (m < 8) ? (acc2[rg] + bb2) : -INFINITY;
        float mx = fmaxf(fmaxf(v0, v1), v2);
        #pragma unroll
        for (int o = 8; o > 0; o >>= 1) mx = fmaxf(mx, __shfl_xor(mx, o, 16));
        float sm = __expf(v0 - mx) + __expf(v1 - mx) + ((m < 8) ? __expf(v2 - mx) : 0.f);
        #pragma unroll
        for (int o = 8; o > 0; o >>= 1) sm += __shfl_xor(sm, o, 16);
        float lse = mx + __logf(sm);
        if (r < N_NODES) {
            out[(size_t)r * C_OUTD + m]      = v0 - lse;
            out[(size_t)r * C_OUTD + 16 + m] = v1 - lse;
            if (m < 8) out[(size_t)r * C_OUTD + 32 + m] = v2 - lse;
        }
    }
}

// ---------------- launcher ----------------

extern "C" void kernel_launch(void* const* d_in, const int* in_sizes, int n_in,
                              void* d_out, int out_size, void* d_ws, size_t ws_size,
                              hipStream_t stream) {
    const int*   ei      = (const int*)d_in[0];
    const int*   row     = ei;
    const int*   col     = ei + NEDGES;
    const float* x_param = (const float*)d_in[1];
    const float* lin1_w  = (const float*)d_in[2];
    const float* lin1_b  = (const float*)d_in[3];
    const float* wq      = (const float*)d_in[4];
    const float* wk      = (const float*)d_in[5];
    const float* wv      = (const float*)d_in[6];
    const float* bq      = (const float*)d_in[7];
    const float* bk      = (const float*)d_in[8];
    const float* bv      = (const float*)d_in[9];
    const float* lin2_w  = (const float*)d_in[10];
    const float* lin2_b  = (const float*)d_in[11];
    float*       out     = (float*)d_out;

    char* wbase = (char*)d_ws;
    size_t off = 0;
    auto alloc = [&](size_t bytes) -> void* {
        off = (off + 255) & ~(size_t)255;
        void* p = wbase + off;
        off += bytes;
        return p;
    };
    int*            degi     = (int*)           alloc((size_t)N_NODES * 4);
    int*            offsets  = (int*)           alloc((size_t)N_NODES * 4);
    int*            cursor   = (int*)           alloc((size_t)N_NODES * 4);
    int*            csr_row  = (int*)           alloc((size_t)ETOT * 4);
    float*          csr_norm = (float*)         alloc((size_t)ETOT * 4);
    unsigned short* xpb      = (unsigned short*)alloc((size_t)N_NODES * F_IN_D * 2);
    unsigned short* W1T      = (unsigned short*)alloc((size_t)H_DIM * F_IN_D * 2);
    unsigned short* WTq      = (unsigned short*)alloc((size_t)3 * H_DIM * H_DIM * 2);
    unsigned short* WTk      = (unsigned short*)alloc((size_t)3 * H_DIM * H_DIM * 2);
    unsigned short* WTv      = (unsigned short*)alloc((size_t)3 * H_DIM * H_DIM * 2);
    unsigned short* W2T      = (unsigned short*)alloc((size_t)48 * H_DIM * 2);
    unsigned short* XHb      = (unsigned short*)alloc((size_t)4 * N_NODES * H_DIM * 2);
    float*          Qb       = (float*)         alloc((size_t)N_NODES * H_DIM * 4);
    unsigned char*  Kb       = (unsigned char*) alloc((size_t)N_NODES * 3 * H_DIM);
    unsigned char*  Vb       = (unsigned char*) alloc((size_t)N_NODES * 3 * H_DIM);

    // fused prep: x cast + weight casts + deg init (independent tasks)
    k_prep<<<3268, 256, 0, stream>>>(x_param, xpb, lin1_w, wq, wk, wv, lin2_w,
                                     W1T, WTq, WTk, WTv, W2T, degi);
    k_deg_count<<<(NEDGES + 255) / 256, 256, 0, stream>>>(col, degi);
    k_scan     <<<1, 256, 0, stream>>>(degi, offsets, cursor);
    k_scatter  <<<(ETOT + 255) / 256, 256, 0, stream>>>(row, col, degi, offsets, cursor,
                                                        csr_row, csr_norm);

    // x0 = relu(x @ W1 + b1)  [MFMA, bf16 out]
    k_lin1_mfma<<<TILES_N, 256, 0, stream>>>(xpb, W1T, lin1_b, XHb, 8);

    for (int l = 0; l < 3; ++l) {
        int t = l + 1;
        k_qkv_mfma<<<(1 + 2 * t) * TILES_N, 256, 0, stream>>>(
            XHb, WTq + (size_t)l * 16384, WTk + (size_t)l * 16384, WTv + (size_t)l * 16384,
            bq + l * H_DIM, bk + l * H_DIM, bv + l * H_DIM,
            Qb, Kb, Vb, l, t);
        unsigned int* Xnext = (unsigned int*)(XHb + (size_t)(l + 1) * N_NODES * H_DIM);
        if (t == 1)
            k_attn_agg<1><<<2500, 256, 0, stream>>>(Qb, (const unsigned int*)Kb,
                                                    (const unsigned int*)Vb, csr_row,
                                                    csr_norm, offsets, degi, Xnext);
        else if (t == 2)
            k_attn_agg<2><<<2500, 256, 0, stream>>>(Qb, (const unsigned int*)Kb,
                                                    (const unsigned int*)Vb, csr_row,
                                                    csr_norm, offsets, degi, Xnext);
        else
            k_attn_agg<3><<<2500, 256, 0, stream>>>(Qb, (const unsigned int*)Kb,
                                                    (const unsigned int*)Vb, csr_row,
                                                    csr_norm, offsets, degi, Xnext);
    }

    k_lin2_mfma<<<TILES_N, 256, 0, stream>>>(XHb + (size_t)3 * N_NODES * H_DIM,
                                             W2T, lin2_b, out);
}

// Round 15
// 271.070 us; speedup vs baseline: 1.0573x; 1.0462x over previous
//
#include <hip/hip_runtime.h>
#include <math.h>

#define N_NODES 10000
#define F_IN_D  256
#define H_DIM   128
#define C_OUTD  40
#define NHEADS  8
#define NEDGES  160000
#define ETOT    (NEDGES + N_NODES)
#define SCALE_F 0.25f  /* 1/sqrt(16) */
#define TILES_N 157    /* ceil(10000/64) */

typedef __attribute__((ext_vector_type(8))) short bf16x8;   // 8 bf16 = 4 VGPRs
typedef __attribute__((ext_vector_type(4))) float f32x4;
typedef __attribute__((ext_vector_type(2))) float f32x2;

__device__ __forceinline__ unsigned short f2bf(float f) {
    unsigned int u = __float_as_uint(f);
    unsigned int r = (u + 0x7FFFu + ((u >> 16) & 1u)) >> 16;  // RNE
    return (unsigned short)r;
}
__device__ __forceinline__ float bf2f(unsigned short h) {
    return __uint_as_float(((unsigned int)h) << 16);
}
__device__ __forceinline__ unsigned char f2fp8(float v) {
    int pk = __builtin_amdgcn_cvt_pk_fp8_f32(v, v, 0, false);  // OCP e4m3fn
    return (unsigned char)(pk & 0xff);
}

// ---------------- graph preprocessing ----------------

__global__ void k_deg_count(const int* __restrict__ col, int* degi) {
    int e = blockIdx.x * 256 + threadIdx.x;
    if (e < NEDGES) atomicAdd(&degi[col[e]], 1);
}

__global__ void k_scan(const int* __restrict__ degi, int* offsets, int* cursor) {
    __shared__ int part[256];
    int tid = threadIdx.x;
    int s = 0;
    if (tid < 250) {
        const int4* d4 = (const int4*)degi;
        for (int i = 0; i < 10; ++i) {
            int4 v = d4[tid * 10 + i];
            s += v.x + v.y + v.z + v.w;
        }
    }
    part[tid] = s;
    __syncthreads();
    for (int off = 1; off < 256; off <<= 1) {
        int v = 0;
        if (tid >= off) v = part[tid - off];
        __syncthreads();
        part[tid] += v;
        __syncthreads();
    }
    if (tid < 250) {
        int base = part[tid] - s;  // exclusive prefix
        int beg = tid * 40;
        for (int i = 0; i < 40; ++i) {
            offsets[beg + i] = base;
            cursor[beg + i]  = 0;
            base += degi[beg + i];
        }
    }
}

__global__ void k_scatter(const int* __restrict__ row, const int* __restrict__ col,
                          const int* __restrict__ degi, const int* __restrict__ offsets,
                          int* cursor, int* csr_row, float* csr_norm) {
    int e = blockIdx.x * 256 + threadIdx.x;
    if (e >= ETOT) return;
    int r, c;
    if (e < NEDGES) { r = row[e]; c = col[e]; }
    else            { r = c = e - NEDGES; }   // self-loop
    int slot = offsets[c] + atomicAdd(&cursor[c], 1);
    float dr = rsqrtf((float)degi[r]);
    float dc = rsqrtf((float)degi[c]);
    csr_row[slot]  = r;
    csr_norm[slot] = dr * dc;
}

// ---------------- fused prep: deg_init + x cast + weight casts (independent) ----

__global__ void k_prep(const float* __restrict__ x, unsigned short* __restrict__ xb,
                       const float* __restrict__ w1, const float* __restrict__ wq,
                       const float* __restrict__ wk, const float* __restrict__ wv,
                       const float* __restrict__ w2,
                       unsigned short* __restrict__ W1T, unsigned short* __restrict__ WTq,
                       unsigned short* __restrict__ WTk, unsigned short* __restrict__ WTv,
                       unsigned short* __restrict__ W2T, int* __restrict__ degi) {
    int b = blockIdx.x;
    if (b < 2500) {
        int i = b * 256 + threadIdx.x;       // 2500*256*4 == 2560000 exactly
        float4 v = *(const float4*)&x[(size_t)i * 4];
        ushort4 o;
        o.x = f2bf(v.x); o.y = f2bf(v.y); o.z = f2bf(v.z); o.w = f2bf(v.w);
        *(ushort4*)&xb[(size_t)i * 4] = o;
    } else if (b < 3228) {
        int e = (b - 2500) * 256 + threadIdx.x;
        if (e < 32768) {
            int n = e >> 8, k = e & 255;
            W1T[e] = f2bf(w1[k * H_DIM + n]);
        } else if (e < 180224) {
            int e2 = e - 32768;
            int mat = e2 >> 14;          // 0..8
            int r   = e2 & 16383;
            int n = r >> 7, k = r & 127;
            int l = mat / 3, ws = mat % 3;
            const float*    src = (ws == 0) ? wq  : (ws == 1) ? wk  : wv;
            unsigned short* dst = (ws == 0) ? WTq : (ws == 1) ? WTk : WTv;
            dst[l * 16384 + n * H_DIM + k] = f2bf(src[l * 16384 + k * H_DIM + n]);
        } else if (e < 186368) {
            int e3 = e - 180224;
            int c = e3 >> 7, k = e3 & 127;
            W2T[c * H_DIM + k] = (c < C_OUTD) ? f2bf(w2[k * C_OUTD + c]) : 0;
        }
    } else {
        int i = (b - 3228) * 256 + threadIdx.x;
        if (i < N_NODES) degi[i] = 1;    // self-loop
    }
}

// ---------------- MFMA lin1: X0 = relu(x_bf @ W1 + b1), bf16 out ----------------
// nct RUNTIME arg (=8): prevents full-unroll spill.

__global__ __launch_bounds__(256) void k_lin1_mfma(const unsigned short* __restrict__ Xb,
                                                   const unsigned short* __restrict__ W1T,
                                                   const float* __restrict__ b1,
                                                   unsigned short* __restrict__ X0,
                                                   int nct) {
    int tid = threadIdx.x;
    int wid = tid >> 6, lane = tid & 63;
    int m = lane & 15, quad = lane >> 4;
    int rowA = blockIdx.x * 64 + wid * 16 + m;      // A overread past N_NODES stays in ws
    bf16x8 af[8];
    const unsigned short* ap = Xb + (size_t)rowA * F_IN_D + quad * 8;
    #pragma unroll
    for (int s = 0; s < 8; ++s)
        af[s] = __builtin_bit_cast(bf16x8, *(const uint4*)(ap + s * 32));
    int row0 = blockIdx.x * 64 + wid * 16 + quad * 4;
    for (int ct = 0; ct < nct; ++ct) {
        int col = ct * 16 + m;
        const unsigned short* bp = W1T + (size_t)col * F_IN_D + quad * 8;
        f32x4 acc = {0.f, 0.f, 0.f, 0.f};
        #pragma unroll
        for (int s = 0; s < 8; ++s) {
            bf16x8 bfr = __builtin_bit_cast(bf16x8, *(const uint4*)(bp + s * 32));
            acc = __builtin_amdgcn_mfma_f32_16x16x32_bf16(af[s], bfr, acc, 0, 0, 0);
        }
        float bb = b1[col];
        #pragma unroll
        for (int rg = 0; rg < 4; ++rg) {
            int r = row0 + rg;
            if (r < N_NODES)
                X0[(size_t)r * H_DIM + col] = f2bf(fmaxf(acc[rg] + bb, 0.f));
        }
    }
}

// ---------------- MFMA fused QKV projection (dual-accumulator interleave) ------
// grid = (1+2t)*TILES_N; mode 0 = Q (fp32 out), 1..t = K slices, t+1..2t = V.
// K/V: fp8 e4m3, layout [node][slice(3)][128].
// nct RUNTIME (=4 col-tile PAIRS). Two independent MFMA chains per iteration
// double the dependency distance (at ~2 waves/SIMD the single-chain stalls
// were exposed). NOTE: full B-preload (R13/R14) REGRESSED +11 us -- keep the
// loop form.

__global__ __launch_bounds__(256) void k_qkv_mfma(const unsigned short* __restrict__ XHb,
                                                  const unsigned short* __restrict__ WTq,
                                                  const unsigned short* __restrict__ WTk,
                                                  const unsigned short* __restrict__ WTv,
                                                  const float* __restrict__ bq,
                                                  const float* __restrict__ bk,
                                                  const float* __restrict__ bv,
                                                  float* __restrict__ Qb,
                                                  unsigned char* __restrict__ Kb,
                                                  unsigned char* __restrict__ Vb,
                                                  int l, int t, int nct) {
    int tid = threadIdx.x;
    int wid = tid >> 6, lane = tid & 63;
    int m = lane & 15, quad = lane >> 4;
    int mi = blockIdx.x / TILES_N;
    int rt = blockIdx.x % TILES_N;
    const unsigned short* WT; const float* bias; int slice, mode;
    if (mi == 0)      { WT = WTq; bias = bq; slice = l;          mode = 0; }
    else if (mi <= t) { WT = WTk; bias = bk; slice = mi - 1;     mode = 1; }
    else              { WT = WTv; bias = bv; slice = mi - t - 1; mode = 2; }
    const unsigned short* A = XHb + (size_t)slice * N_NODES * H_DIM;
    int rowA = rt * 64 + wid * 16 + m;
    bf16x8 af[4];
    const unsigned short* ap = A + (size_t)rowA * H_DIM + quad * 8;
    #pragma unroll
    for (int s = 0; s < 4; ++s)
        af[s] = __builtin_bit_cast(bf16x8, *(const uint4*)(ap + s * 32));
    int row0 = rt * 64 + wid * 16 + quad * 4;
    unsigned char* OutB = (mode == 1) ? Kb : Vb;
    for (int cp = 0; cp < nct; ++cp) {
        int colA = cp * 32 + m;
        int colB = colA + 16;
        const unsigned short* bpA = WT + (size_t)colA * H_DIM + quad * 8;
        const unsigned short* bpB = WT + (size_t)colB * H_DIM + quad * 8;
        bf16x8 bA[4], bB[4];
        #pragma unroll
        for (int s = 0; s < 4; ++s) {
            bA[s] = __builtin_bit_cast(bf16x8, *(const uint4*)(bpA + s * 32));
            bB[s] = __builtin_bit_cast(bf16x8, *(const uint4*)(bpB + s * 32));
        }
        f32x4 accA = {0.f, 0.f, 0.f, 0.f};
        f32x4 accB = {0.f, 0.f, 0.f, 0.f};
        #pragma unroll
        for (int s = 0; s < 4; ++s) {
            accA = __builtin_amdgcn_mfma_f32_16x16x32_bf16(af[s], bA[s], accA, 0, 0, 0);
            accB = __builtin_amdgcn_mfma_f32_16x16x32_bf16(af[s], bB[s], accB, 0, 0, 0);
        }
        float bbA = bias[colA], bbB = bias[colB];
        #pragma unroll
        for (int rg = 0; rg < 4; ++rg) {
            int r = row0 + rg;
            if (r < N_NODES) {
                float vA = accA[rg] + bbA;
                float vB = accB[rg] + bbB;
                if (mode == 0) {
                    Qb[(size_t)r * H_DIM + colA] = vA;
                    Qb[(size_t)r * H_DIM + colB] = vB;
                } else {
                    OutB[((size_t)r * 3 + slice) * H_DIM + colA] = f2fp8(vA);
                    OutB[((size_t)r * 3 + slice) * H_DIM + colB] = f2fp8(vB);
                }
            }
        }
    }
}

// ---------------- fused per-node attention aggregation (wave-per-node) ----------------
// 256 threads = 4 waves = 4 nodes. fp8 K/V: 4 dims/lane (one uint), 32 lanes
// cover 128 dims -> TWO edges per wave-iteration (half = lane>>5).
// NOTE: R13's manual software pipeline REGRESSED: at VGPR=20 / ~8 waves/SIMD
// the gather latency is already TLP-hidden. Keep this plain form.

template <int T>
__global__ __launch_bounds__(256) void k_attn_agg(const float* __restrict__ Q,
                                                  const unsigned int* __restrict__ K,
                                                  const unsigned int* __restrict__ V,
                                                  const int* __restrict__ csr_row,
                                                  const float* __restrict__ csr_norm,
                                                  const int* __restrict__ offsets,
                                                  const int* __restrict__ degi,
                                                  unsigned int* __restrict__ Xout) {
    int tid = threadIdx.x;
    int wid = tid >> 6, lane = tid & 63;
    int half = lane >> 5, ci = lane & 31;
    int n = blockIdx.x * 4 + wid;        // grid 2500*4 == N_NODES exactly
    f32x4 q4;
    {
        float4 t4 = *(const float4*)&Q[(size_t)n * H_DIM + ci * 4];
        q4[0] = t4.x * SCALE_F; q4[1] = t4.y * SCALE_F;
        q4[2] = t4.z * SCALE_F; q4[3] = t4.w * SCALE_F;
    }
    int start = offsets[n];
    int cnt   = degi[n];
    int npairs = (cnt + 1) >> 1;
    float a0 = 0.f, a1 = 0.f, a2 = 0.f, a3 = 0.f;

    for (int j = 0; j < npairs; ++j) {
        int j2 = j * 2 + half;
        int valid = j2 < cnt;
        int idx = start + (valid ? j2 : 0);
        int   r   = csr_row[idx];
        float nrm = valid ? csr_norm[idx] : 0.f;
        const unsigned int* kp = K + (size_t)r * 96 + ci;
        const unsigned int* vp = V + (size_t)r * 96 + ci;
        unsigned int kw[T], vw[T];
        #pragma unroll
        for (int s = 0; s < T; ++s) { kw[s] = kp[s * 32]; vw[s] = vp[s * 32]; }
        float sc[T];
        #pragma unroll
        for (int s = 0; s < T; ++s) {
            f32x2 klo = __builtin_amdgcn_cvt_pk_f32_fp8(kw[s], false);
            f32x2 khi = __builtin_amdgcn_cvt_pk_f32_fp8(kw[s], true);
            float p = q4[0] * klo[0] + q4[1] * klo[1] + q4[2] * khi[0] + q4[3] * khi[1];
            p += __shfl_xor(p, 1, 4);
            p += __shfl_xor(p, 2, 4);
            sc[s] = p;                   // all 4 lanes of the head hold the dot
        }
        float m = 0.f;
        #pragma unroll
        for (int s = 0; s < T; ++s) m = fmaxf(m, sc[s]);
        float den = __expf(-m);          // restricted-softmax null slot
        float mv0 = 0.f, mv1 = 0.f, mv2 = 0.f, mv3 = 0.f;
        #pragma unroll
        for (int s = 0; s < T; ++s) {
            float w = __expf(sc[s] - m);
            den += w;
            f32x2 vlo = __builtin_amdgcn_cvt_pk_f32_fp8(vw[s], false);
            f32x2 vhi = __builtin_amdgcn_cvt_pk_f32_fp8(vw[s], true);
            mv0 += w * vlo[0]; mv1 += w * vlo[1];
            mv2 += w * vhi[0]; mv3 += w * vhi[1];
        }
        float ws = __fdividef(nrm, den);
        a0 += ws * mv0; a1 += ws * mv1; a2 += ws * mv2; a3 += ws * mv3;
    }
    // combine the two edge-halves
    a0 += __shfl_xor(a0, 32, 64);
    a1 += __shfl_xor(a1, 32, 64);
    a2 += __shfl_xor(a2, 32, 64);
    a3 += __shfl_xor(a3, 32, 64);
    if (half == 0) {
        uint2 o;
        o.x = ((unsigned int)f2bf(fmaxf(a1, 0.f)) << 16) | (unsigned int)f2bf(fmaxf(a0, 0.f));
        o.y = ((unsigned int)f2bf(fmaxf(a3, 0.f)) << 16) | (unsigned int)f2bf(fmaxf(a2, 0.f));
        *(uint2*)&Xout[(size_t)n * 64 + ci * 2] = o;   // relu, packed bf16
    }
}

// ---------------- MFMA lin2 + fused log_softmax ----------------

__global__ __launch_bounds__(256) void k_lin2_mfma(const unsigned short* __restrict__ X,
                                                   const unsigned short* __restrict__ W2T,
                                                   const float* __restrict__ b2,
                                                   float* __restrict__ out) {
    int tid = threadIdx.x;
    int wid = tid >> 6, lane = tid & 63;
    int m = lane & 15, quad = lane >> 4;
    int rowA = blockIdx.x * 64 + wid * 16 + m;      // overread past N_NODES stays in ws
    bf16x8 af[4];
    const unsigned short* ap = X + (size_t)rowA * H_DIM + quad * 8;
    #pragma unroll
    for (int s = 0; s < 4; ++s)
        af[s] = __builtin_bit_cast(bf16x8, *(const uint4*)(ap + s * 32));

    f32x4 acc0 = {0.f, 0.f, 0.f, 0.f};
    f32x4 acc1 = {0.f, 0.f, 0.f, 0.f};
    f32x4 acc2 = {0.f, 0.f, 0.f, 0.f};
    const unsigned short* bp0 = W2T + (size_t)(m)      * H_DIM + quad * 8;
    const unsigned short* bp1 = W2T + (size_t)(16 + m) * H_DIM + quad * 8;
    const unsigned short* bp2 = W2T + (size_t)(32 + m) * H_DIM + quad * 8;
    #pragma unroll
    for (int s = 0; s < 4; ++s) {
        bf16x8 b0 = __builtin_bit_cast(bf16x8, *(const uint4*)(bp0 + s * 32));
        acc0 = __builtin_amdgcn_mfma_f32_16x16x32_bf16(af[s], b0, acc0, 0, 0, 0);
        bf16x8 b1 = __builtin_bit_cast(bf16x8, *(const uint4*)(bp1 + s * 32));
        acc1 = __builtin_amdgcn_mfma_f32_16x16x32_bf16(af[s], b1, acc1, 0, 0, 0);
        bf16x8 b2f = __builtin_bit_cast(bf16x8, *(const uint4*)(bp2 + s * 32));
        acc2 = __builtin_amdgcn_mfma_f32_16x16x32_bf16(af[s], b2f, acc2, 0, 0, 0);
    }

    float bb0 = b2[m], bb1 = b2[16 + m];
    float bb2 = (m < 8) ? b2[32 + m] : 0.f;
    int row0 = blockIdx.x * 64 + wid * 16 + quad * 4;
    #pragma unroll
    for (int rg = 0; rg < 4; ++rg) {
        int r = row0 + rg;
        float v0 = acc0[rg] + bb0;
        float v1 = acc1[rg] + bb1;
        float v2 = (m < 8) ? (acc2[rg] + bb2) : -INFINITY;
        float mx = fmaxf(fmaxf(v0, v1), v2);
        #pragma unroll
        for (int o = 8; o > 0; o >>= 1) mx = fmaxf(mx, __shfl_xor(mx, o, 16));
        float sm = __expf(v0 - mx) + __expf(v1 - mx) + ((m < 8) ? __expf(v2 - mx) : 0.f);
        #pragma unroll
        for (int o = 8; o > 0; o >>= 1) sm += __shfl_xor(sm, o, 16);
        float lse = mx + __logf(sm);
        if (r < N_NODES) {
            out[(size_t)r * C_OUTD + m]      = v0 - lse;
            out[(size_t)r * C_OUTD + 16 + m] = v1 - lse;
            if (m < 8) out[(size_t)r * C_OUTD + 32 + m] = v2 - lse;
        }
    }
}

// ---------------- launcher ----------------

extern "C" void kernel_launch(void* const* d_in, const int* in_sizes, int n_in,
                              void* d_out, int out_size, void* d_ws, size_t ws_size,
                              hipStream_t stream) {
    const int*   ei      = (const int*)d_in[0];
    const int*   row     = ei;
    const int*   col     = ei + NEDGES;
    const float* x_param = (const float*)d_in[1];
    const float* lin1_w  = (const float*)d_in[2];
    const float* lin1_b  = (const float*)d_in[3];
    const float* wq      = (const float*)d_in[4];
    const float* wk      = (const float*)d_in[5];
    const float* wv      = (const float*)d_in[6];
    const float* bq      = (const float*)d_in[7];
    const float* bk      = (const float*)d_in[8];
    const float* bv      = (const float*)d_in[9];
    const float* lin2_w  = (const float*)d_in[10];
    const float* lin2_b  = (const float*)d_in[11];
    float*       out     = (float*)d_out;

    char* wbase = (char*)d_ws;
    size_t off = 0;
    auto alloc = [&](size_t bytes) -> void* {
        off = (off + 255) & ~(size_t)255;
        void* p = wbase + off;
        off += bytes;
        return p;
    };
    int*            degi     = (int*)           alloc((size_t)N_NODES * 4);
    int*            offsets  = (int*)           alloc((size_t)N_NODES * 4);
    int*            cursor   = (int*)           alloc((size_t)N_NODES * 4);
    int*            csr_row  = (int*)           alloc((size_t)ETOT * 4);
    float*          csr_norm = (float*)         alloc((size_t)ETOT * 4);
    unsigned short* xpb      = (unsigned short*)alloc((size_t)N_NODES * F_IN_D * 2);
    unsigned short* W1T      = (unsigned short*)alloc((size_t)H_DIM * F_IN_D * 2);
    unsigned short* WTq      = (unsigned short*)alloc((size_t)3 * H_DIM * H_DIM * 2);
    unsigned short* WTk      = (unsigned short*)alloc((size_t)3 * H_DIM * H_DIM * 2);
    unsigned short* WTv      = (unsigned short*)alloc((size_t)3 * H_DIM * H_DIM * 2);
    unsigned short* W2T      = (unsigned short*)alloc((size_t)48 * H_DIM * 2);
    unsigned short* XHb      = (unsigned short*)alloc((size_t)4 * N_NODES * H_DIM * 2);
    float*          Qb       = (float*)         alloc((size_t)N_NODES * H_DIM * 4);
    unsigned char*  Kb       = (unsigned char*) alloc((size_t)N_NODES * 3 * H_DIM);
    unsigned char*  Vb       = (unsigned char*) alloc((size_t)N_NODES * 3 * H_DIM);

    // fused prep: x cast + weight casts + deg init (independent tasks)
    k_prep<<<3268, 256, 0, stream>>>(x_param, xpb, lin1_w, wq, wk, wv, lin2_w,
                                     W1T, WTq, WTk, WTv, W2T, degi);
    k_deg_count<<<(NEDGES + 255) / 256, 256, 0, stream>>>(col, degi);
    k_scan     <<<1, 256, 0, stream>>>(degi, offsets, cursor);
    k_scatter  <<<(ETOT + 255) / 256, 256, 0, stream>>>(row, col, degi, offsets, cursor,
                                                        csr_row, csr_norm);

    // x0 = relu(x @ W1 + b1)  [MFMA, bf16 out]
    k_lin1_mfma<<<TILES_N, 256, 0, stream>>>(xpb, W1T, lin1_b, XHb, 8);

    for (int l = 0; l < 3; ++l) {
        int t = l + 1;
        k_qkv_mfma<<<(1 + 2 * t) * TILES_N, 256, 0, stream>>>(
            XHb, WTq + (size_t)l * 16384, WTk + (size_t)l * 16384, WTv + (size_t)l * 16384,
            bq + l * H_DIM, bk + l * H_DIM, bv + l * H_DIM,
            Qb, Kb, Vb, l, t, 4);
        unsigned int* Xnext = (unsigned int*)(XHb + (size_t)(l + 1) * N_NODES * H_DIM);
        if (t == 1)
            k_attn_agg<1><<<2500, 256, 0, stream>>>(Qb, (const unsigned int*)Kb,
                                                    (const unsigned int*)Vb, csr_row,
                                                    csr_norm, offsets, degi, Xnext);
        else if (t == 2)
            k_attn_agg<2><<<2500, 256, 0, stream>>>(Qb, (const unsigned int*)Kb,
                                                    (const unsigned int*)Vb, csr_row,
                                                    csr_norm, offsets, degi, Xnext);
        else
            k_attn_agg<3><<<2500, 256, 0, stream>>>(Qb, (const unsigned int*)Kb,
                                                    (const unsigned int*)Vb, csr_row,
                                                    csr_norm, offsets, degi, Xnext);
    }

    k_lin2_mfma<<<TILES_N, 256, 0, stream>>>(XHb + (size_t)3 * N_NODES * H_DIM,
                                             W2T, lin2_b, out);
}

// Round 16
// 258.852 us; speedup vs baseline: 1.1072x; 1.0472x over previous
//
#include <hip/hip_runtime.h>
#include <math.h>

#define N_NODES 10000
#define F_IN_D  256
#define H_DIM   128
#define C_OUTD  40
#define NHEADS  8
#define NEDGES  160000
#define ETOT    (NEDGES + N_NODES)
#define SCALE_F 0.25f  /* 1/sqrt(16) */
#define TILES_N 157    /* ceil(10000/64) */

typedef __attribute__((ext_vector_type(8))) short bf16x8;   // 8 bf16 = 4 VGPRs
typedef __attribute__((ext_vector_type(4))) float f32x4;
typedef __attribute__((ext_vector_type(2))) float f32x2;

__device__ __forceinline__ unsigned short f2bf(float f) {
    unsigned int u = __float_as_uint(f);
    unsigned int r = (u + 0x7FFFu + ((u >> 16) & 1u)) >> 16;  // RNE
    return (unsigned short)r;
}
__device__ __forceinline__ float bf2f(unsigned short h) {
    return __uint_as_float(((unsigned int)h) << 16);
}
__device__ __forceinline__ unsigned char f2fp8(float v) {
    int pk = __builtin_amdgcn_cvt_pk_fp8_f32(v, v, 0, false);  // OCP e4m3fn
    return (unsigned char)(pk & 0xff);
}

// ---------------- graph preprocessing ----------------

__global__ void k_deg_count(const int* __restrict__ col, int* degi) {
    int e = blockIdx.x * 256 + threadIdx.x;
    if (e < NEDGES) atomicAdd(&degi[col[e]], 1);
}

__global__ void k_scan(const int* __restrict__ degi, int* offsets, int* cursor) {
    __shared__ int part[256];
    int tid = threadIdx.x;
    int s = 0;
    if (tid < 250) {
        const int4* d4 = (const int4*)degi;
        for (int i = 0; i < 10; ++i) {
            int4 v = d4[tid * 10 + i];
            s += v.x + v.y + v.z + v.w;
        }
    }
    part[tid] = s;
    __syncthreads();
    for (int off = 1; off < 256; off <<= 1) {
        int v = 0;
        if (tid >= off) v = part[tid - off];
        __syncthreads();
        part[tid] += v;
        __syncthreads();
    }
    if (tid < 250) {
        int base = part[tid] - s;  // exclusive prefix
        int beg = tid * 40;
        for (int i = 0; i < 40; ++i) {
            offsets[beg + i] = base;
            cursor[beg + i]  = 0;
            base += degi[beg + i];
        }
    }
}

__global__ void k_scatter(const int* __restrict__ row, const int* __restrict__ col,
                          const int* __restrict__ degi, const int* __restrict__ offsets,
                          int* cursor, int* csr_row, float* csr_norm) {
    int e = blockIdx.x * 256 + threadIdx.x;
    if (e >= ETOT) return;
    int r, c;
    if (e < NEDGES) { r = row[e]; c = col[e]; }
    else            { r = c = e - NEDGES; }   // self-loop
    int slot = offsets[c] + atomicAdd(&cursor[c], 1);
    float dr = rsqrtf((float)degi[r]);
    float dc = rsqrtf((float)degi[c]);
    csr_row[slot]  = r;
    csr_norm[slot] = dr * dc;
}

// ---------------- fused prep: weight casts + deg_init (x-cast fused into lin1) ----

__global__ void k_prep(const float* __restrict__ w1, const float* __restrict__ wq,
                       const float* __restrict__ wk, const float* __restrict__ wv,
                       const float* __restrict__ w2,
                       unsigned short* __restrict__ W1T, unsigned short* __restrict__ WTq,
                       unsigned short* __restrict__ WTk, unsigned short* __restrict__ WTv,
                       unsigned short* __restrict__ W2T, int* __restrict__ degi) {
    int b = blockIdx.x;
    if (b < 728) {
        int e = b * 256 + threadIdx.x;
        if (e < 32768) {
            int n = e >> 8, k = e & 255;
            W1T[e] = f2bf(w1[k * H_DIM + n]);
        } else if (e < 180224) {
            int e2 = e - 32768;
            int mat = e2 >> 14;          // 0..8
            int r   = e2 & 16383;
            int n = r >> 7, k = r & 127;
            int l = mat / 3, ws = mat % 3;
            const float*    src = (ws == 0) ? wq  : (ws == 1) ? wk  : wv;
            unsigned short* dst = (ws == 0) ? WTq : (ws == 1) ? WTk : WTv;
            dst[l * 16384 + n * H_DIM + k] = f2bf(src[l * 16384 + k * H_DIM + n]);
        } else if (e < 186368) {
            int e3 = e - 180224;
            int c = e3 >> 7, k = e3 & 127;
            W2T[c * H_DIM + k] = (c < C_OUTD) ? f2bf(w2[k * C_OUTD + c]) : 0;
        }
    } else {
        int i = (b - 728) * 256 + threadIdx.x;
        if (i < N_NODES) degi[i] = 1;    // self-loop
    }
}

// ---------------- MFMA lin1: X0 = relu(x @ W1 + b1), fp32 in, bf16 out ---------
// Reads x_param fp32 directly (cast fused -- saves a 15 MB prep pass).
// rowA CLAMPED: x_param is an input buffer, overread would leave the alloc.
// nct RUNTIME arg (=8): prevents full-unroll spill.

__global__ __launch_bounds__(256) void k_lin1_mfma(const float* __restrict__ X,
                                                   const unsigned short* __restrict__ W1T,
                                                   const float* __restrict__ b1,
                                                   unsigned short* __restrict__ X0,
                                                   int nct) {
    int tid = threadIdx.x;
    int wid = tid >> 6, lane = tid & 63;
    int m = lane & 15, quad = lane >> 4;
    int rowA = blockIdx.x * 64 + wid * 16 + m;
    int rowc = rowA < N_NODES ? rowA : N_NODES - 1;
    bf16x8 af[8];
    const float* ap = X + (size_t)rowc * F_IN_D + quad * 8;
    #pragma unroll
    for (int s = 0; s < 8; ++s) {
        float4 lo = *(const float4*)(ap + s * 32);
        float4 hi = *(const float4*)(ap + s * 32 + 4);
        union { unsigned short u[8]; bf16x8 v; } pk;
        pk.u[0] = f2bf(lo.x); pk.u[1] = f2bf(lo.y);
        pk.u[2] = f2bf(lo.z); pk.u[3] = f2bf(lo.w);
        pk.u[4] = f2bf(hi.x); pk.u[5] = f2bf(hi.y);
        pk.u[6] = f2bf(hi.z); pk.u[7] = f2bf(hi.w);
        af[s] = pk.v;
    }
    int row0 = blockIdx.x * 64 + wid * 16 + quad * 4;
    for (int ct = 0; ct < nct; ++ct) {
        int col = ct * 16 + m;
        const unsigned short* bp = W1T + (size_t)col * F_IN_D + quad * 8;
        f32x4 acc = {0.f, 0.f, 0.f, 0.f};
        #pragma unroll
        for (int s = 0; s < 8; ++s) {
            bf16x8 bfr = __builtin_bit_cast(bf16x8, *(const uint4*)(bp + s * 32));
            acc = __builtin_amdgcn_mfma_f32_16x16x32_bf16(af[s], bfr, acc, 0, 0, 0);
        }
        float bb = b1[col];
        #pragma unroll
        for (int rg = 0; rg < 4; ++rg) {
            int r = row0 + rg;
            if (r < N_NODES)
                X0[(size_t)r * H_DIM + col] = f2bf(fmaxf(acc[rg] + bb, 0.f));
        }
    }
}

// ---------------- MFMA fused QKV projection (dual-accumulator interleave) ------
// grid = (1+2t)*TILES_N; mode 0 = Q (bf16 out), 1..t = K slices, t+1..2t = V.
// K/V: fp8 e4m3, layout [node][slice(3)][128]. Q: bf16 (halves Q traffic).
// nct RUNTIME (=4 col-tile PAIRS); two independent MFMA chains per iteration.
// NOTE: full B-preload (R13/R14) REGRESSED +11 us -- keep the loop form.

__global__ __launch_bounds__(256) void k_qkv_mfma(const unsigned short* __restrict__ XHb,
                                                  const unsigned short* __restrict__ WTq,
                                                  const unsigned short* __restrict__ WTk,
                                                  const unsigned short* __restrict__ WTv,
                                                  const float* __restrict__ bq,
                                                  const float* __restrict__ bk,
                                                  const float* __restrict__ bv,
                                                  unsigned short* __restrict__ Qb,
                                                  unsigned char* __restrict__ Kb,
                                                  unsigned char* __restrict__ Vb,
                                                  int l, int t, int nct) {
    int tid = threadIdx.x;
    int wid = tid >> 6, lane = tid & 63;
    int m = lane & 15, quad = lane >> 4;
    int mi = blockIdx.x / TILES_N;
    int rt = blockIdx.x % TILES_N;
    const unsigned short* WT; const float* bias; int slice, mode;
    if (mi == 0)      { WT = WTq; bias = bq; slice = l;          mode = 0; }
    else if (mi <= t) { WT = WTk; bias = bk; slice = mi - 1;     mode = 1; }
    else              { WT = WTv; bias = bv; slice = mi - t - 1; mode = 2; }
    const unsigned short* A = XHb + (size_t)slice * N_NODES * H_DIM;
    int rowA = rt * 64 + wid * 16 + m;
    bf16x8 af[4];
    const unsigned short* ap = A + (size_t)rowA * H_DIM + quad * 8;
    #pragma unroll
    for (int s = 0; s < 4; ++s)
        af[s] = __builtin_bit_cast(bf16x8, *(const uint4*)(ap + s * 32));
    int row0 = rt * 64 + wid * 16 + quad * 4;
    unsigned char* OutB = (mode == 1) ? Kb : Vb;
    for (int cp = 0; cp < nct; ++cp) {
        int colA = cp * 32 + m;
        int colB = colA + 16;
        const unsigned short* bpA = WT + (size_t)colA * H_DIM + quad * 8;
        const unsigned short* bpB = WT + (size_t)colB * H_DIM + quad * 8;
        bf16x8 bA[4], bB[4];
        #pragma unroll
        for (int s = 0; s < 4; ++s) {
            bA[s] = __builtin_bit_cast(bf16x8, *(const uint4*)(bpA + s * 32));
            bB[s] = __builtin_bit_cast(bf16x8, *(const uint4*)(bpB + s * 32));
        }
        f32x4 accA = {0.f, 0.f, 0.f, 0.f};
        f32x4 accB = {0.f, 0.f, 0.f, 0.f};
        #pragma unroll
        for (int s = 0; s < 4; ++s) {
            accA = __builtin_amdgcn_mfma_f32_16x16x32_bf16(af[s], bA[s], accA, 0, 0, 0);
            accB = __builtin_amdgcn_mfma_f32_16x16x32_bf16(af[s], bB[s], accB, 0, 0, 0);
        }
        float bbA = bias[colA], bbB = bias[colB];
        #pragma unroll
        for (int rg = 0; rg < 4; ++rg) {
            int r = row0 + rg;
            if (r < N_NODES) {
                float vA = accA[rg] + bbA;
                float vB = accB[rg] + bbB;
                if (mode == 0) {
                    Qb[(size_t)r * H_DIM + colA] = f2bf(vA);
                    Qb[(size_t)r * H_DIM + colB] = f2bf(vB);
                } else {
                    OutB[((size_t)r * 3 + slice) * H_DIM + colA] = f2fp8(vA);
                    OutB[((size_t)r * 3 + slice) * H_DIM + colB] = f2fp8(vB);
                }
            }
        }
    }
}

// ---------------- fused per-node attention aggregation (wave-per-node) ----------------
// 256 threads = 4 waves = 4 nodes. fp8 K/V, 8 dims/lane (uint2), 16 lanes per
// edge -> FOUR edges per wave-iteration (quarter = lane>>4). Head = ci>>1,
// dot-reduce width 2; quarter-combine via shfl_xor 16/32 at end.
// Q: bf16 (uint4 = 8 dims/lane). K,V viewed as uint [node][slice(3)][32].
// NOTE: R13's manual software pipeline REGRESSED -- keep plain loop form.

template <int T>
__global__ __launch_bounds__(256) void k_attn_agg(const unsigned short* __restrict__ Q,
                                                  const unsigned int* __restrict__ K,
                                                  const unsigned int* __restrict__ V,
                                                  const int* __restrict__ csr_row,
                                                  const float* __restrict__ csr_norm,
                                                  const int* __restrict__ offsets,
                                                  const int* __restrict__ degi,
                                                  unsigned int* __restrict__ Xout) {
    int tid = threadIdx.x;
    int wid = tid >> 6, lane = tid & 63;
    int quarter = lane >> 4, ci = lane & 15;
    int n = blockIdx.x * 4 + wid;        // grid 2500*4 == N_NODES exactly
    float q[8];
    {
        uint4 qp = *(const uint4*)&Q[(size_t)n * H_DIM + ci * 8];
        q[0] = __uint_as_float(qp.x << 16) * SCALE_F;
        q[1] = __uint_as_float(qp.x & 0xffff0000u) * SCALE_F;
        q[2] = __uint_as_float(qp.y << 16) * SCALE_F;
        q[3] = __uint_as_float(qp.y & 0xffff0000u) * SCALE_F;
        q[4] = __uint_as_float(qp.z << 16) * SCALE_F;
        q[5] = __uint_as_float(qp.z & 0xffff0000u) * SCALE_F;
        q[6] = __uint_as_float(qp.w << 16) * SCALE_F;
        q[7] = __uint_as_float(qp.w & 0xffff0000u) * SCALE_F;
    }
    int start = offsets[n];
    int cnt   = degi[n];
    int nq = (cnt + 3) >> 2;
    float a[8];
    #pragma unroll
    for (int i = 0; i < 8; ++i) a[i] = 0.f;

    for (int j = 0; j < nq; ++j) {
        int j4 = j * 4 + quarter;
        int valid = j4 < cnt;
        int idx = start + (valid ? j4 : 0);
        int   r   = csr_row[idx];
        float nrm = valid ? csr_norm[idx] : 0.f;
        const uint2* kp = (const uint2*)&K[(size_t)r * 96 + ci * 2];
        const uint2* vp = (const uint2*)&V[(size_t)r * 96 + ci * 2];
        uint2 kw[T], vw[T];
        #pragma unroll
        for (int s = 0; s < T; ++s) { kw[s] = kp[s * 16]; vw[s] = vp[s * 16]; }
        float sc[T];
        #pragma unroll
        for (int s = 0; s < T; ++s) {
            f32x2 k0 = __builtin_amdgcn_cvt_pk_f32_fp8(kw[s].x, false);
            f32x2 k1 = __builtin_amdgcn_cvt_pk_f32_fp8(kw[s].x, true);
            f32x2 k2 = __builtin_amdgcn_cvt_pk_f32_fp8(kw[s].y, false);
            f32x2 k3 = __builtin_amdgcn_cvt_pk_f32_fp8(kw[s].y, true);
            float p = q[0] * k0[0] + q[1] * k0[1] + q[2] * k1[0] + q[3] * k1[1]
                    + q[4] * k2[0] + q[5] * k2[1] + q[6] * k3[0] + q[7] * k3[1];
            p += __shfl_xor(p, 1, 2);    // head = ci>>1: pair-reduce
            sc[s] = p;
        }
        float m = 0.f;
        #pragma unroll
        for (int s = 0; s < T; ++s) m = fmaxf(m, sc[s]);
        float den = __expf(-m);          // restricted-softmax null slot
        float mv[8];
        #pragma unroll
        for (int i = 0; i < 8; ++i) mv[i] = 0.f;
        #pragma unroll
        for (int s = 0; s < T; ++s) {
            float w = __expf(sc[s] - m);
            den += w;
            f32x2 v0 = __builtin_amdgcn_cvt_pk_f32_fp8(vw[s].x, false);
            f32x2 v1 = __builtin_amdgcn_cvt_pk_f32_fp8(vw[s].x, true);
            f32x2 v2 = __builtin_amdgcn_cvt_pk_f32_fp8(vw[s].y, false);
            f32x2 v3 = __builtin_amdgcn_cvt_pk_f32_fp8(vw[s].y, true);
            mv[0] += w * v0[0]; mv[1] += w * v0[1];
            mv[2] += w * v1[0]; mv[3] += w * v1[1];
            mv[4] += w * v2[0]; mv[5] += w * v2[1];
            mv[6] += w * v3[0]; mv[7] += w * v3[1];
        }
        float ws = __fdividef(nrm, den);
        #pragma unroll
        for (int i = 0; i < 8; ++i) a[i] += ws * mv[i];
    }
    // combine the four edge-quarters
    #pragma unroll
    for (int i = 0; i < 8; ++i) {
        a[i] += __shfl_xor(a[i], 16, 64);
        a[i] += __shfl_xor(a[i], 32, 64);
    }
    if (quarter == 0) {
        uint4 o;
        o.x = ((unsigned int)f2bf(fmaxf(a[1], 0.f)) << 16) | (unsigned int)f2bf(fmaxf(a[0], 0.f));
        o.y = ((unsigned int)f2bf(fmaxf(a[3], 0.f)) << 16) | (unsigned int)f2bf(fmaxf(a[2], 0.f));
        o.z = ((unsigned int)f2bf(fmaxf(a[5], 0.f)) << 16) | (unsigned int)f2bf(fmaxf(a[4], 0.f));
        o.w = ((unsigned int)f2bf(fmaxf(a[7], 0.f)) << 16) | (unsigned int)f2bf(fmaxf(a[6], 0.f));
        *(uint4*)&Xout[(size_t)n * 64 + ci * 4] = o;   // relu, packed bf16
    }
}

// ---------------- MFMA lin2 + fused log_softmax ----------------

__global__ __launch_bounds__(256) void k_lin2_mfma(const unsigned short* __restrict__ X,
                                                   const unsigned short* __restrict__ W2T,
                                                   const float* __restrict__ b2,
                                                   float* __restrict__ out) {
    int tid = threadIdx.x;
    int wid = tid >> 6, lane = tid & 63;
    int m = lane & 15, quad = lane >> 4;
    int rowA = blockIdx.x * 64 + wid * 16 + m;      // overread past N_NODES stays in ws
    bf16x8 af[4];
    const unsigned short* ap = X + (size_t)rowA * H_DIM + quad * 8;
    #pragma unroll
    for (int s = 0; s < 4; ++s)
        af[s] = __builtin_bit_cast(bf16x8, *(const uint4*)(ap + s * 32));

    f32x4 acc0 = {0.f, 0.f, 0.f, 0.f};
    f32x4 acc1 = {0.f, 0.f, 0.f, 0.f};
    f32x4 acc2 = {0.f, 0.f, 0.f, 0.f};
    const unsigned short* bp0 = W2T + (size_t)(m)      * H_DIM + quad * 8;
    const unsigned short* bp1 = W2T + (size_t)(16 + m) * H_DIM + quad * 8;
    const unsigned short* bp2 = W2T + (size_t)(32 + m) * H_DIM + quad * 8;
    #pragma unroll
    for (int s = 0; s < 4; ++s) {
        bf16x8 b0 = __builtin_bit_cast(bf16x8, *(const uint4*)(bp0 + s * 32));
        acc0 = __builtin_amdgcn_mfma_f32_16x16x32_bf16(af[s], b0, acc0, 0, 0, 0);
        bf16x8 b1 = __builtin_bit_cast(bf16x8, *(const uint4*)(bp1 + s * 32));
        acc1 = __builtin_amdgcn_mfma_f32_16x16x32_bf16(af[s], b1, acc1, 0, 0, 0);
        bf16x8 b2f = __builtin_bit_cast(bf16x8, *(const uint4*)(bp2 + s * 32));
        acc2 = __builtin_amdgcn_mfma_f32_16x16x32_bf16(af[s], b2f, acc2, 0, 0, 0);
    }

    float bb0 = b2[m], bb1 = b2[16 + m];
    float bb2 = (m < 8) ? b2[32 + m] : 0.f;
    int row0 = blockIdx.x * 64 + wid * 16 + quad * 4;
    #pragma unroll
    for (int rg = 0; rg < 4; ++rg) {
        int r = row0 + rg;
        float v0 = acc0[rg] + bb0;
        float v1 = acc1[rg] + bb1;
        float v2 = (m < 8) ? (acc2[rg] + bb2) : -INFINITY;
        float mx = fmaxf(fmaxf(v0, v1), v2);
        #pragma unroll
        for (int o = 8; o > 0; o >>= 1) mx = fmaxf(mx, __shfl_xor(mx, o, 16));
        float sm = __expf(v0 - mx) + __expf(v1 - mx) + ((m < 8) ? __expf(v2 - mx) : 0.f);
        #pragma unroll
        for (int o = 8; o > 0; o >>= 1) sm += __shfl_xor(sm, o, 16);
        float lse = mx + __logf(sm);
        if (r < N_NODES) {
            out[(size_t)r * C_OUTD + m]      = v0 - lse;
            out[(size_t)r * C_OUTD + 16 + m] = v1 - lse;
            if (m < 8) out[(size_t)r * C_OUTD + 32 + m] = v2 - lse;
        }
    }
}

// ---------------- launcher ----------------

extern "C" void kernel_launch(void* const* d_in, const int* in_sizes, int n_in,
                              void* d_out, int out_size, void* d_ws, size_t ws_size,
                              hipStream_t stream) {
    const int*   ei      = (const int*)d_in[0];
    const int*   row     = ei;
    const int*   col     = ei + NEDGES;
    const float* x_param = (const float*)d_in[1];
    const float* lin1_w  = (const float*)d_in[2];
    const float* lin1_b  = (const float*)d_in[3];
    const float* wq      = (const float*)d_in[4];
    const float* wk      = (const float*)d_in[5];
    const float* wv      = (const float*)d_in[6];
    const float* bq      = (const float*)d_in[7];
    const float* bk      = (const float*)d_in[8];
    const float* bv      = (const float*)d_in[9];
    const float* lin2_w  = (const float*)d_in[10];
    const float* lin2_b  = (const float*)d_in[11];
    float*       out     = (float*)d_out;

    char* wbase = (char*)d_ws;
    size_t off = 0;
    auto alloc = [&](size_t bytes) -> void* {
        off = (off + 255) & ~(size_t)255;
        void* p = wbase + off;
        off += bytes;
        return p;
    };
    int*            degi     = (int*)           alloc((size_t)N_NODES * 4);
    int*            offsets  = (int*)           alloc((size_t)N_NODES * 4);
    int*            cursor   = (int*)           alloc((size_t)N_NODES * 4);
    int*            csr_row  = (int*)           alloc((size_t)ETOT * 4);
    float*          csr_norm = (float*)         alloc((size_t)ETOT * 4);
    unsigned short* W1T      = (unsigned short*)alloc((size_t)H_DIM * F_IN_D * 2);
    unsigned short* WTq      = (unsigned short*)alloc((size_t)3 * H_DIM * H_DIM * 2);
    unsigned short* WTk      = (unsigned short*)alloc((size_t)3 * H_DIM * H_DIM * 2);
    unsigned short* WTv      = (unsigned short*)alloc((size_t)3 * H_DIM * H_DIM * 2);
    unsigned short* W2T      = (unsigned short*)alloc((size_t)48 * H_DIM * 2);
    unsigned short* XHb      = (unsigned short*)alloc((size_t)4 * N_NODES * H_DIM * 2);
    unsigned short* Qb       = (unsigned short*)alloc((size_t)N_NODES * H_DIM * 2);
    unsigned char*  Kb       = (unsigned char*) alloc((size_t)N_NODES * 3 * H_DIM);
    unsigned char*  Vb       = (unsigned char*) alloc((size_t)N_NODES * 3 * H_DIM);

    // fused prep: weight casts + deg init
    k_prep<<<768, 256, 0, stream>>>(lin1_w, wq, wk, wv, lin2_w,
                                    W1T, WTq, WTk, WTv, W2T, degi);
    k_deg_count<<<(NEDGES + 255) / 256, 256, 0, stream>>>(col, degi);
    k_scan     <<<1, 256, 0, stream>>>(degi, offsets, cursor);
    k_scatter  <<<(ETOT + 255) / 256, 256, 0, stream>>>(row, col, degi, offsets, cursor,
                                                        csr_row, csr_norm);

    // x0 = relu(x @ W1 + b1)  [MFMA, fp32 in (cast fused), bf16 out]
    k_lin1_mfma<<<TILES_N, 256, 0, stream>>>(x_param, W1T, lin1_b, XHb, 8);

    for (int l = 0; l < 3; ++l) {
        int t = l + 1;
        k_qkv_mfma<<<(1 + 2 * t) * TILES_N, 256, 0, stream>>>(
            XHb, WTq + (size_t)l * 16384, WTk + (size_t)l * 16384, WTv + (size_t)l * 16384,
            bq + l * H_DIM, bk + l * H_DIM, bv + l * H_DIM,
            Qb, Kb, Vb, l, t, 4);
        unsigned int* Xnext = (unsigned int*)(XHb + (size_t)(l + 1) * N_NODES * H_DIM);
        if (t == 1)
            k_attn_agg<1><<<2500, 256, 0, stream>>>(Qb, (const unsigned int*)Kb,
                                                    (const unsigned int*)Vb, csr_row,
                                                    csr_norm, offsets, degi, Xnext);
        else if (t == 2)
            k_attn_agg<2><<<2500, 256, 0, stream>>>(Qb, (const unsigned int*)Kb,
                                                    (const unsigned int*)Vb, csr_row,
                                                    csr_norm, offsets, degi, Xnext);
        else
            k_attn_agg<3><<<2500, 256, 0, stream>>>(Qb, (const unsigned int*)Kb,
                                                    (const unsigned int*)Vb, csr_row,
                                                    csr_norm, offsets, degi, Xnext);
    }

    k_lin2_mfma<<<TILES_N, 256, 0, stream>>>(XHb + (size_t)3 * N_NODES * H_DIM,
                                             W2T, lin2_b, out);
}